// Round 5
// baseline (166.490 us; speedup 1.0000x reference)
//
#include <hip/hip_runtime.h>

// B=64, K=8, H=W=128 (HW=16384). float32 in/out.
// out[0] = loss scalar; out[1..] = pred_perm (B,K,H,W) flat.
//
// Pipeline (256B memset + 2 kernels):
//   cost_kernel    : barrier-free partial sums of cross[i][j] = sum_hw t_j*log(p_i+eps)
//                    and ent[j] = sum_hw t_j*log(t_j+eps), register-double-buffered
//                    loads (10x 1KB per wave in flight). Last-finishing block per
//                    batch (atomic counter) reduces the 8 partials and runs the
//                    Held-Karp DP -> ws_inv (col->row), ws_loss[b].
//   permute_kernel : pure permuted copy with aligned float4 stores; block 0 sums
//                    ws_loss -> out[0].

#define BB 64
#define KK 8
#define HW 16384
#define SPANS 8      // cost blocks per batch
#define SPAN 2048    // floats per span per row
#define EPSF 1e-15f

// ---------- compile-time mask table: all 255 nonzero 8-bit masks, level-ordered by popcount ----------
struct MaskTab {
    unsigned char masks[255];
    int off[9];
};

constexpr MaskTab make_tab() {
    MaskTab t{};
    int idx = 0;
    for (int p = 1; p <= 8; ++p) {
        t.off[p - 1] = idx;
        for (int m = 1; m < 256; ++m) {
            int c = 0;
            for (int b = 0; b < 8; ++b) c += (m >> b) & 1;
            if (c == p) t.masks[idx++] = (unsigned char)m;
        }
    }
    t.off[8] = idx;
    return t;
}

__constant__ MaskTab kTab = make_tab();

__device__ __forceinline__ float dot4(float4 t, float4 l) {
    return t.x * l.x + t.y * l.y + t.z * l.z + t.w * l.w;
}

__device__ __forceinline__ float4 log4(float4 a) {
    float4 r;
    r.x = __logf(a.x + EPSF); r.y = __logf(a.y + EPSF);
    r.z = __logf(a.z + EPSF); r.w = __logf(a.w + EPSF);
    return r;
}

struct Chunk {
    float4 p0, p1;
    float4 t[8];
};

__device__ __forceinline__ Chunk ldchunk(const float* __restrict__ p0,
                                         const float* __restrict__ p1,
                                         const float* __restrict__ tb, int off) {
    Chunk c;
    c.p0 = *(const float4*)(p0 + off);
    c.p1 = *(const float4*)(p1 + off);
#pragma unroll
    for (int j = 0; j < 8; ++j) c.t[j] = *(const float4*)(tb + j * HW + off);
    return c;
}

// ---------- phase 1: partial cross/ent sums + fused per-batch DP ----------
// grid: B*SPANS=512 blocks of 256 threads (4 waves). Wave w owns pred rows {2w,2w+1}
// (16 cross accs) and ent rows {2w,2w+1} (taken from its own aug loads). No LDS, no
// barriers in the hot loop; cur/nxt register double-buffer keeps 10 KB of loads in
// flight per wave. The 8th-finishing block per batch reduces partials + runs the DP.
__global__ __launch_bounds__(256) void cost_kernel(const float* __restrict__ pred,
                                                   const float* __restrict__ aug,
                                                   float* __restrict__ part,    // [512][72]
                                                   int* __restrict__ ctr,       // [64], zeroed
                                                   int* __restrict__ ws_inv,    // [64][8] col->row
                                                   float* __restrict__ ws_loss) // [64]
{
    __shared__ float C[64];
    __shared__ float dp[256];
    __shared__ int   choice[256];
    __shared__ int   lastf;

    const int blk  = blockIdx.x;          // b*SPANS + s
    const int b    = blk >> 3;
    const int s    = blk & 7;
    const int tid  = threadIdx.x;
    const int lane = tid & 63;
    const int w2   = __builtin_amdgcn_readfirstlane(2 * (tid >> 6)); // scalar: ent rows
    const int wave = w2 >> 1;

    const size_t base = (size_t)b * (KK * HW) + (size_t)s * SPAN;
    const float* p0 = pred + base + (size_t)w2 * HW;
    const float* p1 = p0 + HW;
    const float* tb = aug + base;
    const int l4 = lane * 4;

    float acc[16];
#pragma unroll
    for (int v = 0; v < 16; ++v) acc[v] = 0.f;
    float e0 = 0.f, e1 = 0.f;

    Chunk cur = ldchunk(p0, p1, tb, l4);
#pragma unroll
    for (int c = 0; c < 8; ++c) {
        Chunk nxt;
        if (c < 7) nxt = ldchunk(p0, p1, tb, (c + 1) * 256 + l4);  // in flight during compute

        const float4 la = log4(cur.p0);
        const float4 lc = log4(cur.p1);
#pragma unroll
        for (int j = 0; j < 8; ++j) {
            const float4 tv = cur.t[j];
            acc[j]     += dot4(tv, la);
            acc[8 + j] += dot4(tv, lc);
            if (j == w2)     e0 += dot4(tv, log4(tv));   // scalar cond -> s_cbranch skip
            if (j == w2 + 1) e1 += dot4(tv, log4(tv));
        }
        if (c < 7) cur = nxt;
    }

    // wave-wide butterfly reduce: 18 values
#pragma unroll
    for (int v = 0; v < 16; ++v) {
        float sv = acc[v];
#pragma unroll
        for (int d = 1; d < 64; d <<= 1) sv += __shfl_xor(sv, d);
        acc[v] = sv;
    }
#pragma unroll
    for (int d = 1; d < 64; d <<= 1) e0 += __shfl_xor(e0, d);
#pragma unroll
    for (int d = 1; d < 64; d <<= 1) e1 += __shfl_xor(e1, d);

    if (lane == 0) {
        float* dst = part + (size_t)blk * 72;
#pragma unroll
        for (int j = 0; j < 8; ++j) {
            dst[16 * wave + j]     = acc[j];       // cross[i=2w][j]
            dst[16 * wave + 8 + j] = acc[8 + j];   // cross[i=2w+1][j]
        }
        dst[64 + w2]     = e0;                     // ent[2w]
        dst[64 + w2 + 1] = e1;                     // ent[2w+1]
    }

    // --- completion protocol: last block of this batch runs the DP ---
    __syncthreads();                               // drains vmcnt: part stores done
    if (tid == 0) {
        __threadfence();                           // release part writes
        const int old = atomicAdd(&ctr[b], 1);     // device-scope
        lastf = (old == SPANS - 1) ? 1 : 0;
    }
    __syncthreads();
    if (!lastf) return;
    __threadfence();                               // acquire other blocks' part writes

    // reduce 8 span-partials -> C[i*8+j] = ent[j] - cross[i][j]
    if (tid < 64) {
        const float* pb = part + (size_t)(b * 8) * 72;
        float ssum = 0.f;
#pragma unroll
        for (int s8 = 0; s8 < 8; ++s8) ssum += pb[s8 * 72 + tid];
        float e = 0.f;
        if (tid < 8) {
#pragma unroll
            for (int s8 = 0; s8 < 8; ++s8) e += pb[s8 * 72 + 64 + tid];
        }
        const float entj = __shfl(e, tid & 7);
        C[tid] = entj - ssum;
    }
    if (tid == 0) dp[0] = 0.f;
    __syncthreads();

    // Held-Karp DP over 255 masks, level-ordered by popcount; 32 mask slots/pass
    const int grp = tid >> 3;
    const int j   = tid & 7;
    for (int lvl = 1; lvl <= 8; ++lvl) {
        const int start = kTab.off[lvl - 1];
        const int end   = kTab.off[lvl];
        const float* Crow = &C[(lvl - 1) * 8];
        for (int bse = start; bse < end; bse += 32) {
            const int mi = bse + grp;
            if (mi < end) {
                const int M = kTab.masks[mi];
                float v  = 1e30f;
                int   bj = 0;
                if (M & (1 << j)) {
                    v  = dp[M ^ (1 << j)] + Crow[j];
                    bj = j;
                }
#pragma unroll
                for (int d = 1; d < 8; d <<= 1) {
                    const float ov = __shfl_xor(v, d);
                    const int   oj = __shfl_xor(bj, d);
                    if (ov < v) { v = ov; bj = oj; }
                }
                if (j == 0) { dp[M] = v; choice[M] = bj; }
            }
        }
        __syncthreads();
    }

    if (tid == 0) {
        int mask = 255;
        for (int r = 7; r >= 0; --r) {
            const int jj = choice[mask];
            ws_inv[b * 8 + jj] = r;                // column jj takes pred row r
            mask ^= 1 << jj;
        }
        ws_loss[b] = dp[255] * (1.0f / (16384.0f * 512.0f));
    }
}

// ---------- phase 2: pure permuted copy + loss finalize ----------
// grid: 2048 blocks of 256 threads; block handles quarter q=blk&3 of pair p=blk>>2.
// out+1 row base is 4B-aligned; element 3 of each row is 16B-aligned, so the middle
// 4095 quads go out as aligned float4; head 3 + tail 1 elements by one thread.
__global__ __launch_bounds__(256) void permute_kernel(const float* __restrict__ pred,
                                                      const int* __restrict__ ws_inv,
                                                      const float* __restrict__ ws_loss,
                                                      float* __restrict__ out)
{
    const int blk  = blockIdx.x;
    const int pair = blk >> 2;        // b*8 + jcol
    const int q    = blk & 3;
    const int b    = pair >> 3;
    const int tid  = threadIdx.x;

    const int src_row = ws_inv[pair]; // block-uniform scalar load
    const float* src = pred + ((size_t)(b << 3) + src_row) * HW;
    float*      drow = out + 1 + (size_t)pair * HW;

#pragma unroll
    for (int m = 0; m < 4; ++m) {
        const int f = q * 1024 + tid + 256 * m;   // quad index in [0,4096)
        const int e = 3 + 4 * f;
        if (f < 4095) {
            float4 v;
            v.x = src[e]; v.y = src[e + 1]; v.z = src[e + 2]; v.w = src[e + 3];
            *(float4*)(drow + e) = v;             // 16B-aligned
        } else {                                  // f==4095: head 3 + tail 1
            drow[0] = src[0]; drow[1] = src[1]; drow[2] = src[2];
            drow[16383] = src[16383];
        }
    }

    if (blk == 0 && tid < 64) {
        float v = ws_loss[tid];
#pragma unroll
        for (int d = 1; d < 64; d <<= 1) v += __shfl_xor(v, d);
        if (tid == 0) out[0] = v;
    }
}

extern "C" void kernel_launch(void* const* d_in, const int* in_sizes, int n_in,
                              void* d_out, int out_size, void* d_ws, size_t ws_size,
                              hipStream_t stream) {
    const float* pred = (const float*)d_in[0];
    const float* aug  = (const float*)d_in[1];
    float* out = (float*)d_out;

    int*   ctr     = (int*)d_ws;                     // 64 ints
    float* part    = (float*)d_ws + 64;              // 512*72 floats
    int*   ws_inv  = (int*)(part + 512 * 72);        // 512 ints
    float* ws_loss = (float*)(ws_inv + 512);         // 64 floats

    hipMemsetAsync(ctr, 0, 64 * sizeof(int), stream);

    cost_kernel<<<dim3(BB * SPANS), dim3(256), 0, stream>>>(pred, aug, part, ctr, ws_inv, ws_loss);
    permute_kernel<<<dim3(2048), dim3(256), 0, stream>>>(pred, ws_inv, ws_loss, out);
}